// Round 1
// baseline (224.656 us; speedup 1.0000x reference)
//
#include <hip/hip_runtime.h>
#include <hip/hip_bf16.h>

// Problem constants (from reference): B=16, MAX_LEN=100, LOC_MAX=20000, EMB=256, D_DELTA=2
#define NB 16
#define MLEN 100
#define MPAD 112            // MLEN padded to multiple of 16
#define EMBD 256
#define LMAX 20000
#define LT 128              // l-tile (N tile)
#define KC 64               // K chunk
#define NKC (EMBD / KC)     // 4
#define THREADS 256
#define PPITCH 132          // P row pitch (floats), breaks bank alignment, 8B-aligned rows

typedef __attribute__((ext_vector_type(4))) float f32x4;
typedef __attribute__((ext_vector_type(8))) short bf16x8;   // 8 bf16 in 4 VGPRs

struct GemmLds {
    unsigned short Shi[MPAD * KC];  // A operand hi, [m][k] XOR-swizzled rows (128 B/row)
    unsigned short Slo[MPAD * KC];  // A operand lo
    unsigned short Ehi[LT * KC];    // B operand hi, [n][k] XOR-swizzled rows
    unsigned short Elo[LT * KC];    // B operand lo
};                                   // 61440 B
struct StreamLds {
    float P2[MLEN * PPITCH];        // P[m][l], 52800 B
    float red[4 * LT];              // cross-wave reduction, 2048 B
};
union LdsU { GemmLds g; StreamLds s; };

// bf16 RNE conversion via bit ops (no API ambiguity)
__device__ __forceinline__ unsigned short f2bf(float x) {
    union { float f; unsigned u; } a; a.f = x;
    unsigned r = a.u + 0x7FFFu + ((a.u >> 16) & 1u);
    return (unsigned short)(r >> 16);
}
__device__ __forceinline__ float bf2f(unsigned short h) {
    union { unsigned u; float f; } a; a.u = ((unsigned)h) << 16;
    return a.f;
}

__global__ __launch_bounds__(THREADS, 2)
void fused_attn_kernel(const float* __restrict__ attn,    // [B][MLEN][EMBD]
                       const float* __restrict__ sdelta,  // [B][MLEN][LMAX][2]
                       const float* __restrict__ embt,    // [LMAX+1][EMBD]
                       const float* __restrict__ vw,      // [MLEN]
                       float* __restrict__ out) {         // [B][LMAX]
    __shared__ LdsU u;
    const int t    = threadIdx.x;
    const int b    = blockIdx.x;
    const int lt0  = blockIdx.y * LT;
    const int wave = t >> 6;
    const int lane = t & 63;
    const int llo  = lane & 15;   // row/col within 16x16 tile
    const int lhi  = lane >> 4;   // k-group / acc row group

    // GEMM accumulators: each wave owns n-range [wave*32, wave*32+32), all 7 m-tiles
    f32x4 acc[7][2];
    #pragma unroll
    for (int i = 0; i < 7; ++i)
        #pragma unroll
        for (int j = 0; j < 2; ++j)
            acc[i][j] = (f32x4){0.f, 0.f, 0.f, 0.f};

    const int row0 = t >> 4;   // staging: 16 rows per pass
    const int e4   = t & 15;   // staging: float4 index within 64-elem K chunk

    // ---------------- Phase A: P[m][l] = sum_e (vw[m]*attn[b][m][e]) * emb[1+l][e]
    // hi/lo bf16 split, 3 MFMA passes => ~f32 accuracy.
    for (int kc = 0; kc < NKC; ++kc) {
        // stage A operand: S = vw[m]*attn[b][m][kc*64 + ...], rows 0..111 (pad rows -> 0)
        #pragma unroll
        for (int p = 0; p < 7; ++p) {
            const int row = row0 + p * 16;
            f32x4 v = {0.f, 0.f, 0.f, 0.f};
            float w = 0.f;
            if (row < MLEN) {
                w = vw[row];
                v = *reinterpret_cast<const f32x4*>(
                        attn + ((size_t)b * MLEN + row) * EMBD + kc * KC + e4 * 4);
            }
            unsigned h0, h1, w0, w1;
            {
                unsigned short hA, lA, hB, lB;
                float x0 = v[0] * w; hA = f2bf(x0); lA = f2bf(x0 - bf2f(hA));
                float x1 = v[1] * w; hB = f2bf(x1); lB = f2bf(x1 - bf2f(hB));
                h0 = hA | ((unsigned)hB << 16); w0 = lA | ((unsigned)lB << 16);
                float x2 = v[2] * w; hA = f2bf(x2); lA = f2bf(x2 - bf2f(hA));
                float x3 = v[3] * w; hB = f2bf(x3); lB = f2bf(x3 - bf2f(hB));
                h1 = hA | ((unsigned)hB << 16); w1 = lA | ((unsigned)lB << 16);
            }
            const int off = row * 128 + ((e4 * 8) ^ ((row & 7) << 4));  // XOR swizzle (G4)
            *reinterpret_cast<uint2*>(reinterpret_cast<char*>(u.g.Shi) + off) = make_uint2(h0, h1);
            *reinterpret_cast<uint2*>(reinterpret_cast<char*>(u.g.Slo) + off) = make_uint2(w0, w1);
        }
        // stage B operand: emb_cand rows lt0..lt0+127 (emb_table row 1+l), OOB -> 0
        #pragma unroll
        for (int p = 0; p < 8; ++p) {
            const int n  = row0 + p * 16;
            const int gl = lt0 + n;
            f32x4 v = {0.f, 0.f, 0.f, 0.f};
            if (gl < LMAX) {
                v = *reinterpret_cast<const f32x4*>(
                        embt + (size_t)(1 + gl) * EMBD + kc * KC + e4 * 4);
            }
            unsigned h0, h1, w0, w1;
            {
                unsigned short hA, lA, hB, lB;
                float x0 = v[0]; hA = f2bf(x0); lA = f2bf(x0 - bf2f(hA));
                float x1 = v[1]; hB = f2bf(x1); lB = f2bf(x1 - bf2f(hB));
                h0 = hA | ((unsigned)hB << 16); w0 = lA | ((unsigned)lB << 16);
                float x2 = v[2]; hA = f2bf(x2); lA = f2bf(x2 - bf2f(hA));
                float x3 = v[3]; hB = f2bf(x3); lB = f2bf(x3 - bf2f(hB));
                h1 = hA | ((unsigned)hB << 16); w1 = lA | ((unsigned)lB << 16);
            }
            const int off = n * 128 + ((e4 * 8) ^ ((n & 7) << 4));
            *reinterpret_cast<uint2*>(reinterpret_cast<char*>(u.g.Ehi) + off) = make_uint2(h0, h1);
            *reinterpret_cast<uint2*>(reinterpret_cast<char*>(u.g.Elo) + off) = make_uint2(w0, w1);
        }
        __syncthreads();

        // MFMA: 2 k-steps of 32, 7 m-tiles x 2 n-tiles per wave, 3 passes (hh, hl, lh)
        #pragma unroll
        for (int kk = 0; kk < 2; ++kk) {
            const int kbyte = kk * 64 + lhi * 16;
            bf16x8 bh[2], bl[2];
            #pragma unroll
            for (int nt = 0; nt < 2; ++nt) {
                const int col  = wave * 32 + nt * 16 + llo;
                const int boff = col * 128 + (kbyte ^ ((col & 7) << 4));
                bh[nt] = *reinterpret_cast<const bf16x8*>(reinterpret_cast<const char*>(u.g.Ehi) + boff);
                bl[nt] = *reinterpret_cast<const bf16x8*>(reinterpret_cast<const char*>(u.g.Elo) + boff);
            }
            #pragma unroll
            for (int mt = 0; mt < 7; ++mt) {
                const int row  = mt * 16 + llo;
                const int aoff = row * 128 + (kbyte ^ ((row & 7) << 4));
                bf16x8 ah = *reinterpret_cast<const bf16x8*>(reinterpret_cast<const char*>(u.g.Shi) + aoff);
                bf16x8 al = *reinterpret_cast<const bf16x8*>(reinterpret_cast<const char*>(u.g.Slo) + aoff);
                #pragma unroll
                for (int nt = 0; nt < 2; ++nt) {
                    acc[mt][nt] = __builtin_amdgcn_mfma_f32_16x16x32_bf16(ah, bh[nt], acc[mt][nt], 0, 0, 0);
                    acc[mt][nt] = __builtin_amdgcn_mfma_f32_16x16x32_bf16(ah, bl[nt], acc[mt][nt], 0, 0, 0);
                    acc[mt][nt] = __builtin_amdgcn_mfma_f32_16x16x32_bf16(al, bh[nt], acc[mt][nt], 0, 0, 0);
                }
            }
        }
        __syncthreads();
    }

    // Park P in LDS. C/D layout (verified): col = lane&15, row = (lane>>4)*4 + i
    #pragma unroll
    for (int mt = 0; mt < 7; ++mt) {
        #pragma unroll
        for (int nt = 0; nt < 2; ++nt) {
            const int col = wave * 32 + nt * 16 + llo;
            #pragma unroll
            for (int i = 0; i < 4; ++i) {
                const int m = mt * 16 + lhi * 4 + i;
                if (m < MLEN) u.s.P2[m * PPITCH + col] = acc[mt][nt][i];
            }
        }
    }
    __syncthreads();

    // ---------------- Phase B: stream self_delta (256 MB, exactly once, float4 coalesced)
    // out[b][l] = sum_m (sd0+sd1) * P[m][l]; wave q handles m = q, q+4, ...
    float accE = 0.f, accO = 0.f;
    const bool valid = (lt0 + 2 * lane) < LMAX;   // pair (l_even,l_odd) validity
    const float* sdb = sdelta + ((size_t)(b * MLEN) * LMAX + lt0) * 2 + lane * 4;
    #pragma unroll 5
    for (int i = 0; i < 25; ++i) {
        const int m = wave + 4 * i;
        f32x4 v = {0.f, 0.f, 0.f, 0.f};
        if (valid) v = *reinterpret_cast<const f32x4*>(sdb + (size_t)m * (LMAX * 2));
        const float2 p = *reinterpret_cast<const float2*>(&u.s.P2[m * PPITCH + 2 * lane]);
        accE += (v[0] + v[1]) * p.x;
        accO += (v[2] + v[3]) * p.y;
    }
    *reinterpret_cast<float2*>(&u.s.red[wave * LT + 2 * lane]) = make_float2(accE, accO);
    __syncthreads();
    if (t < LT) {
        const int l = lt0 + t;
        if (l < LMAX) {
            float s = u.s.red[t] + u.s.red[LT + t] + u.s.red[2 * LT + t] + u.s.red[3 * LT + t];
            out[(size_t)b * LMAX + l] = s;
        }
    }
}

extern "C" void kernel_launch(void* const* d_in, const int* in_sizes, int n_in,
                              void* d_out, int out_size, void* d_ws, size_t ws_size,
                              hipStream_t stream) {
    const float* attn   = (const float*)d_in[0];  // self_attn  [16][100][256] f32
    const float* sdelta = (const float*)d_in[1];  // self_delta [16][100][20000][2] f32
    // d_in[2] = traj_len (int64) — unused by the reference computation
    const float* embt   = (const float*)d_in[3];  // emb_table  [20001][256] f32
    const float* vw     = (const float*)d_in[4];  // value_w    [1][100] f32
    float* out = (float*)d_out;                   // [16][20000] f32

    dim3 grid(NB, (LMAX + LT - 1) / LT);          // b fastest-varying -> emb L2 reuse
    fused_attn_kernel<<<grid, THREADS, 0, stream>>>(attn, sdelta, embt, vw, out);
}

// Round 2
// 195.550 us; speedup vs baseline: 1.1488x; 1.1488x over previous
//
#include <hip/hip_runtime.h>

// Problem constants: B=16, MAX_LEN=100, LOC_MAX=20000, EMB=256, D_DELTA=2
#define NB 16
#define MLEN 100
#define EMBD 256
#define LMAX 20000
#define NLT 157            // l-tiles of 128 (157*128 = 20096)
#define NT16 1256          // n-tiles of 16  (NLT*8)
#define NKS 8              // K=256 / 32
#define NBFRAG (NT16 * NKS)      // 10048 B-fragments (64 lanes x 16B each)
#define NAFRAG (NB * 7 * NKS)    // 896 A-fragments
#define BTASKS (NBFRAG * 64)     // 643072
#define ATASKS (NAFRAG * 64)     // 57344
#define PREP_BLOCKS ((BTASKS + ATASKS) / 256)  // 2736 exactly

typedef __attribute__((ext_vector_type(4))) float f32x4;
typedef __attribute__((ext_vector_type(8))) short bf16x8;

__device__ __forceinline__ unsigned short f2bf(float x) {
    union { float f; unsigned u; } a; a.f = x;
    unsigned r = a.u + 0x7FFFu + ((a.u >> 16) & 1u);
    return (unsigned short)(r >> 16);
}
__device__ __forceinline__ float bf2f(unsigned short h) {
    union { unsigned u; float f; } a; a.u = ((unsigned)h) << 16;
    return a.f;
}

// split 8 f32 (scaled by w) into packed hi/lo bf16 (RNE), ~2^-17 combined accuracy
__device__ __forceinline__ void split8(f32x4 v0, f32x4 v1, float w, uint4& hi, uint4& lo) {
    float x[8] = { v0[0]*w, v0[1]*w, v0[2]*w, v0[3]*w, v1[0]*w, v1[1]*w, v1[2]*w, v1[3]*w };
    unsigned h[8], l[8];
    #pragma unroll
    for (int j = 0; j < 8; ++j) {
        unsigned short hh = f2bf(x[j]);
        h[j] = hh;
        l[j] = f2bf(x[j] - bf2f(hh));
    }
    hi = make_uint4(h[0] | (h[1] << 16), h[2] | (h[3] << 16), h[4] | (h[5] << 16), h[6] | (h[7] << 16));
    lo = make_uint4(l[0] | (l[1] << 16), l[2] | (l[3] << 16), l[4] | (l[5] << 16), l[6] | (l[7] << 16));
}

// ---------------- Kernel 1: one-time conversion + MFMA-fragment packing ----------------
// B frag f = t16*8+ks, lane: emb_cand[t16*16 + (lane&15)][ks*32 + (lane>>4)*8 .. +8]
// A frag f = (b*7+mt)*8+ks, lane: vw[m]*attn[b][m][...], m = mt*16 + (lane&15)
__global__ __launch_bounds__(256)
void prep_kernel(const float* __restrict__ attn, const float* __restrict__ embt,
                 const float* __restrict__ vw,
                 unsigned short* __restrict__ Bhi, unsigned short* __restrict__ Blo,
                 unsigned short* __restrict__ Ahi, unsigned short* __restrict__ Alo) {
    const int gid = blockIdx.x * 256 + threadIdx.x;
    if (gid < BTASKS) {
        const int lane = gid & 63;
        const int f    = gid >> 6;
        const int ks   = f & 7;
        const int t16  = f >> 3;
        const int n    = t16 * 16 + (lane & 15);
        const int k    = ks * 32 + (lane >> 4) * 8;
        f32x4 v0 = {0.f,0.f,0.f,0.f}, v1 = {0.f,0.f,0.f,0.f};
        if (n < LMAX) {
            const float* p = embt + (size_t)(n + 1) * EMBD + k;
            v0 = *reinterpret_cast<const f32x4*>(p);
            v1 = *reinterpret_cast<const f32x4*>(p + 4);
        }
        uint4 hi, lo;
        split8(v0, v1, 1.f, hi, lo);
        reinterpret_cast<uint4*>(Bhi)[gid] = hi;
        reinterpret_cast<uint4*>(Blo)[gid] = lo;
    } else {
        const int gid2 = gid - BTASKS;
        const int lane = gid2 & 63;
        const int f    = gid2 >> 6;
        const int ks   = f & 7;
        const int bm   = f >> 3;
        const int mt   = bm % 7;
        const int b    = bm / 7;
        const int m    = mt * 16 + (lane & 15);
        const int k    = ks * 32 + (lane >> 4) * 8;
        f32x4 v0 = {0.f,0.f,0.f,0.f}, v1 = {0.f,0.f,0.f,0.f};
        float w = 0.f;
        if (m < MLEN) {
            w = vw[m];
            const float* p = attn + ((size_t)b * MLEN + m) * EMBD + k;
            v0 = *reinterpret_cast<const f32x4*>(p);
            v1 = *reinterpret_cast<const f32x4*>(p + 4);
        }
        uint4 hi, lo;
        split8(v0, v1, w, hi, lo);
        reinterpret_cast<uint4*>(Ahi)[gid2] = hi;
        reinterpret_cast<uint4*>(Alo)[gid2] = lo;
    }
}

// ---------------- Kernel 2: zero-LDS fused GEMM (3-pass hi/lo) + sdelta stream ----------------
__global__ __launch_bounds__(256, 3)
void main_kernel(const unsigned short* __restrict__ Bhi, const unsigned short* __restrict__ Blo,
                 const unsigned short* __restrict__ Ahi, const unsigned short* __restrict__ Alo,
                 const float* __restrict__ sdelta, float* __restrict__ out) {
    const int b    = blockIdx.x;
    const int lt   = blockIdx.y;
    const int w    = threadIdx.x >> 6;
    const int lane = threadIdx.x & 63;
    const int llo  = lane & 15;
    const int lhi  = lane >> 4;

    f32x4 acc[7][2];
    #pragma unroll
    for (int i = 0; i < 7; ++i) {
        acc[i][0] = (f32x4){0.f,0.f,0.f,0.f};
        acc[i][1] = (f32x4){0.f,0.f,0.f,0.f};
    }

    // GEMM: wave w owns cols [lt*128 + w*32, +32) = n-tiles (lt*8 + 2w, lt*8 + 2w + 1)
    const int t16b = lt * 8 + w * 2;
    for (int ks = 0; ks < NKS; ++ks) {
        const size_t bo0 = ((size_t)((t16b + 0) * NKS + ks) * 64 + lane) * 8;
        const size_t bo1 = ((size_t)((t16b + 1) * NKS + ks) * 64 + lane) * 8;
        const bf16x8 bh0 = *reinterpret_cast<const bf16x8*>(Bhi + bo0);
        const bf16x8 bl0 = *reinterpret_cast<const bf16x8*>(Blo + bo0);
        const bf16x8 bh1 = *reinterpret_cast<const bf16x8*>(Bhi + bo1);
        const bf16x8 bl1 = *reinterpret_cast<const bf16x8*>(Blo + bo1);
        #pragma unroll
        for (int mt = 0; mt < 7; ++mt) {
            const size_t ao = ((size_t)((b * 7 + mt) * NKS + ks) * 64 + lane) * 8;
            const bf16x8 ah = *reinterpret_cast<const bf16x8*>(Ahi + ao);
            const bf16x8 al = *reinterpret_cast<const bf16x8*>(Alo + ao);
            acc[mt][0] = __builtin_amdgcn_mfma_f32_16x16x32_bf16(ah, bh0, acc[mt][0], 0, 0, 0);
            acc[mt][1] = __builtin_amdgcn_mfma_f32_16x16x32_bf16(ah, bh1, acc[mt][1], 0, 0, 0);
            acc[mt][0] = __builtin_amdgcn_mfma_f32_16x16x32_bf16(ah, bl0, acc[mt][0], 0, 0, 0);
            acc[mt][1] = __builtin_amdgcn_mfma_f32_16x16x32_bf16(ah, bl1, acc[mt][1], 0, 0, 0);
            acc[mt][0] = __builtin_amdgcn_mfma_f32_16x16x32_bf16(al, bh0, acc[mt][0], 0, 0, 0);
            acc[mt][1] = __builtin_amdgcn_mfma_f32_16x16x32_bf16(al, bh1, acc[mt][1], 0, 0, 0);
        }
    }

    // Stream sdelta directly against the accumulator.
    // C/D layout: col = lane&15 (+nt*16), row m = mt*16 + (lane>>4)*4 + i  [verified r1]
    float res0 = 0.f, res1 = 0.f;
    const int colb = lt * 128 + w * 32;
    const float* sdb = sdelta + (size_t)b * MLEN * LMAX * 2;
    const int l0 = colb + llo;
    const int l1 = colb + 16 + llo;
    const bool lv0 = (l0 < LMAX);
    const bool lv1 = (l1 < LMAX);
    #pragma unroll
    for (int mt = 0; mt < 7; ++mt) {
        #pragma unroll
        for (int i = 0; i < 4; ++i) {
            const int m = mt * 16 + lhi * 4 + i;
            const bool mv = (m < MLEN);
            const float* rp = sdb + (size_t)m * (LMAX * 2);
            float2 v0 = make_float2(0.f, 0.f), v1 = make_float2(0.f, 0.f);
            if (mv && lv0) v0 = *reinterpret_cast<const float2*>(rp + (size_t)l0 * 2);
            if (mv && lv1) v1 = *reinterpret_cast<const float2*>(rp + (size_t)l1 * 2);
            res0 += (v0.x + v0.y) * acc[mt][0][i];
            res1 += (v1.x + v1.y) * acc[mt][1][i];
        }
    }
    // reduce over lhi (lanes ^16, ^32 share the same column)
    res0 += __shfl_xor(res0, 16);
    res0 += __shfl_xor(res0, 32);
    res1 += __shfl_xor(res1, 16);
    res1 += __shfl_xor(res1, 32);
    if (lhi == 0) {
        if (lv0) out[(size_t)b * LMAX + l0] = res0;
        if (lv1) out[(size_t)b * LMAX + l1] = res1;
    }
}

// ---------------- Fallback (ws too small): straightforward f32 compute ----------------
__global__ __launch_bounds__(256)
void fallback_kernel(const float* __restrict__ attn, const float* __restrict__ sdelta,
                     const float* __restrict__ embt, const float* __restrict__ vw,
                     float* __restrict__ out) {
    const int idx = blockIdx.x * 256 + threadIdx.x;
    if (idx >= NB * LMAX) return;
    const int b = idx / LMAX;
    const int l = idx % LMAX;
    float s = 0.f;
    for (int m = 0; m < MLEN; ++m) {
        const float* ar = attn + ((size_t)b * MLEN + m) * EMBD;
        const float* er = embt + (size_t)(l + 1) * EMBD;
        float dot = 0.f;
        for (int e = 0; e < EMBD; ++e) dot += ar[e] * er[e];
        const size_t so = (((size_t)b * MLEN + m) * LMAX + l) * 2;
        s += dot * vw[m] * (sdelta[so] + sdelta[so + 1]);
    }
    out[idx] = s;
}

extern "C" void kernel_launch(void* const* d_in, const int* in_sizes, int n_in,
                              void* d_out, int out_size, void* d_ws, size_t ws_size,
                              hipStream_t stream) {
    const float* attn   = (const float*)d_in[0];  // [16][100][256] f32
    const float* sdelta = (const float*)d_in[1];  // [16][100][20000][2] f32
    // d_in[2] = traj_len — unused by the reference computation
    const float* embt   = (const float*)d_in[3];  // [20001][256] f32
    const float* vw     = (const float*)d_in[4];  // [1][100] f32
    float* out = (float*)d_out;                   // [16][20000] f32

    const size_t bfragShorts = (size_t)NBFRAG * 512;  // 5,144,576
    const size_t afragShorts = (size_t)NAFRAG * 512;  //   458,752
    const size_t needed = (2 * bfragShorts + 2 * afragShorts) * sizeof(unsigned short); // 22,413,312 B

    if (ws_size >= needed) {
        unsigned short* Bhi = (unsigned short*)d_ws;
        unsigned short* Blo = Bhi + bfragShorts;
        unsigned short* Ahi = Blo + bfragShorts;
        unsigned short* Alo = Ahi + afragShorts;
        prep_kernel<<<PREP_BLOCKS, 256, 0, stream>>>(attn, embt, vw, Bhi, Blo, Ahi, Alo);
        main_kernel<<<dim3(NB, NLT), 256, 0, stream>>>(Bhi, Blo, Ahi, Alo, sdelta, out);
    } else {
        fallback_kernel<<<(NB * LMAX + 255) / 256, 256, 0, stream>>>(attn, sdelta, embt, vw, out);
    }
}

// Round 3
// 119.235 us; speedup vs baseline: 1.8841x; 1.6400x over previous
//
#include <hip/hip_runtime.h>

// Problem constants: B=16, MAX_LEN=100, LOC_MAX=20000, EMB=256, D_DELTA=2
#define NB 16
#define MLEN 100
#define EMBD 256
#define LMAX 20000
#define NLT 157            // l-tiles of 128 (157*128 = 20096)
#define NT16 1256          // n-tiles of 16  (NLT*8)
#define NKS 8              // K=256 / 32
#define NBFRAG (NT16 * NKS)      // 10048 B-fragments (64 lanes x 16B each)
#define NAFRAG (NB * NKS * 7)    // 896 A-fragments, layout [b][ks][mt]
#define BTASKS (NBFRAG * 64)     // 643072
#define ATASKS (NAFRAG * 64)     // 57344
#define PREP_BLOCKS ((BTASKS + ATASKS) / 256)  // 2736 exactly

typedef __attribute__((ext_vector_type(4))) float f32x4;
typedef __attribute__((ext_vector_type(8))) short bf16x8;
typedef const __attribute__((address_space(1))) unsigned int* as1_u32p;
typedef __attribute__((address_space(3))) unsigned int* as3_u32p;

__device__ __forceinline__ unsigned short f2bf(float x) {
    union { float f; unsigned u; } a; a.f = x;
    unsigned r = a.u + 0x7FFFu + ((a.u >> 16) & 1u);
    return (unsigned short)(r >> 16);
}
__device__ __forceinline__ float bf2f(unsigned short h) {
    union { unsigned u; float f; } a; a.u = ((unsigned)h) << 16;
    return a.f;
}

__device__ __forceinline__ void split8(f32x4 v0, f32x4 v1, float w, uint4& hi, uint4& lo) {
    float x[8] = { v0[0]*w, v0[1]*w, v0[2]*w, v0[3]*w, v1[0]*w, v1[1]*w, v1[2]*w, v1[3]*w };
    unsigned h[8], l[8];
    #pragma unroll
    for (int j = 0; j < 8; ++j) {
        unsigned short hh = f2bf(x[j]);
        h[j] = hh;
        l[j] = f2bf(x[j] - bf2f(hh));
    }
    hi = make_uint4(h[0] | (h[1] << 16), h[2] | (h[3] << 16), h[4] | (h[5] << 16), h[6] | (h[7] << 16));
    lo = make_uint4(l[0] | (l[1] << 16), l[2] | (l[3] << 16), l[4] | (l[5] << 16), l[6] | (l[7] << 16));
}

// ---------------- Kernel 1: one-time conversion + MFMA-fragment packing ----------------
// B frag f = t16*NKS+ks : emb_cand[t16*16 + (lane&15)][ks*32 + (lane>>4)*8 ..+8]
// A frag f = (b*NKS+ks)*7+mt : vw[m]*attn[b][m][..], m = mt*16 + (lane&15)   (ks-major!)
__global__ __launch_bounds__(256)
void prep_kernel(const float* __restrict__ attn, const float* __restrict__ embt,
                 const float* __restrict__ vw,
                 unsigned short* __restrict__ Bhi, unsigned short* __restrict__ Blo,
                 unsigned short* __restrict__ Ahi, unsigned short* __restrict__ Alo) {
    const int gid = blockIdx.x * 256 + threadIdx.x;
    if (gid < BTASKS) {
        const int lane = gid & 63;
        const int f    = gid >> 6;
        const int ks   = f & 7;
        const int t16  = f >> 3;
        const int n    = t16 * 16 + (lane & 15);
        const int k    = ks * 32 + (lane >> 4) * 8;
        f32x4 v0 = {0.f,0.f,0.f,0.f}, v1 = {0.f,0.f,0.f,0.f};
        if (n < LMAX) {
            const float* p = embt + (size_t)(n + 1) * EMBD + k;
            v0 = *reinterpret_cast<const f32x4*>(p);
            v1 = *reinterpret_cast<const f32x4*>(p + 4);
        }
        uint4 hi, lo;
        split8(v0, v1, 1.f, hi, lo);
        reinterpret_cast<uint4*>(Bhi)[gid] = hi;
        reinterpret_cast<uint4*>(Blo)[gid] = lo;
    } else {
        const int gid2 = gid - BTASKS;
        const int lane = gid2 & 63;
        const int f    = gid2 >> 6;     // (b*NKS+ks)*7 + mt
        const int mt   = f % 7;
        const int t    = f / 7;
        const int ks   = t & 7;
        const int b    = t >> 3;
        const int m    = mt * 16 + (lane & 15);
        const int k    = ks * 32 + (lane >> 4) * 8;
        f32x4 v0 = {0.f,0.f,0.f,0.f}, v1 = {0.f,0.f,0.f,0.f};
        float w = 0.f;
        if (m < MLEN) {
            w = vw[m];
            const float* p = attn + ((size_t)b * MLEN + m) * EMBD + k;
            v0 = *reinterpret_cast<const f32x4*>(p);
            v1 = *reinterpret_cast<const f32x4*>(p + 4);
        }
        uint4 hi, lo;
        split8(v0, v1, w, hi, lo);
        reinterpret_cast<uint4*>(Ahi)[gid2] = hi;
        reinterpret_cast<uint4*>(Alo)[gid2] = lo;
    }
}

// ---------------- Kernel 2: LDS-staged pipelined GEMM (3-pass hi/lo) + sdelta stream ----------------
__global__ __launch_bounds__(256, 3)
void main_kernel(const unsigned short* __restrict__ Bhi, const unsigned short* __restrict__ Blo,
                 const unsigned short* __restrict__ Ahi, const unsigned short* __restrict__ Alo,
                 const float* __restrict__ sdelta, float* __restrict__ out) {
    __shared__ __align__(16) unsigned short Alds[2 * 14 * 512];  // 2 bufs x 14 frags x 1KB = 28672 B
    const int b    = blockIdx.x;
    const int lt   = blockIdx.y;
    const int w    = threadIdx.x >> 6;
    const int lane = threadIdx.x & 63;
    const int llo  = lane & 15;
    const int lhi  = lane >> 4;

    f32x4 acc[7][2];
    #pragma unroll
    for (int i = 0; i < 7; ++i) {
        acc[i][0] = (f32x4){0.f,0.f,0.f,0.f};
        acc[i][1] = (f32x4){0.f,0.f,0.f,0.f};
    }

    // async-stage A[b][ks] (14 frags: u<7 -> hi[mt=u], u>=7 -> lo[mt=u-7]) into Alds buf
    auto stageA = [&](int ks, int buf) {
        #pragma unroll
        for (int j = 0; j < 4; ++j) {
            const int u = j * 4 + w;          // wave-uniform
            if (u < 14) {
                const int mt = (u < 7) ? u : u - 7;
                const unsigned short* base = (u < 7) ? Ahi : Alo;
                const unsigned short* src = base + ((size_t)((b * NKS + ks) * 7 + mt)) * 512 + lane * 8;
                unsigned short* dst = &Alds[buf * 7168 + u * 512];   // uniform base; HW adds lane*16B
                __builtin_amdgcn_global_load_lds((as1_u32p)(const void*)src,
                                                 (as3_u32p)(void*)dst, 16, 0, 0);
            }
        }
    };
    const int t16b = lt * 8 + w * 2;
    auto loadB = [&](int ks, bf16x8* dst) {
        const size_t bo0 = ((size_t)((t16b + 0) * NKS + ks) * 64 + lane) * 8;
        const size_t bo1 = ((size_t)((t16b + 1) * NKS + ks) * 64 + lane) * 8;
        dst[0] = *reinterpret_cast<const bf16x8*>(Bhi + bo0);
        dst[1] = *reinterpret_cast<const bf16x8*>(Blo + bo0);
        dst[2] = *reinterpret_cast<const bf16x8*>(Bhi + bo1);
        dst[3] = *reinterpret_cast<const bf16x8*>(Blo + bo1);
    };

    bf16x8 Bc[4], Bn[4];
    stageA(0, 0);
    loadB(0, Bc);
    __syncthreads();

    #pragma unroll
    for (int ks = 0; ks < NKS; ++ks) {
        if (ks + 1 < NKS) {
            stageA(ks + 1, (ks + 1) & 1);     // async into other buffer
            loadB(ks + 1, Bn);                // in-flight across the MFMA cluster
        }
        #pragma unroll
        for (int mt = 0; mt < 7; ++mt) {
            const bf16x8 ah = *reinterpret_cast<const bf16x8*>(&Alds[(ks & 1) * 7168 + mt * 512 + lane * 8]);
            const bf16x8 al = *reinterpret_cast<const bf16x8*>(&Alds[(ks & 1) * 7168 + (7 + mt) * 512 + lane * 8]);
            acc[mt][0] = __builtin_amdgcn_mfma_f32_16x16x32_bf16(ah, Bc[0], acc[mt][0], 0, 0, 0);
            acc[mt][1] = __builtin_amdgcn_mfma_f32_16x16x32_bf16(ah, Bc[2], acc[mt][1], 0, 0, 0);
            acc[mt][0] = __builtin_amdgcn_mfma_f32_16x16x32_bf16(ah, Bc[1], acc[mt][0], 0, 0, 0);
            acc[mt][1] = __builtin_amdgcn_mfma_f32_16x16x32_bf16(ah, Bc[3], acc[mt][1], 0, 0, 0);
            acc[mt][0] = __builtin_amdgcn_mfma_f32_16x16x32_bf16(al, Bc[0], acc[mt][0], 0, 0, 0);
            acc[mt][1] = __builtin_amdgcn_mfma_f32_16x16x32_bf16(al, Bc[2], acc[mt][1], 0, 0, 0);
        }
        __syncthreads();   // drains own vmcnt (stages + Bn) then barrier
        if (ks + 1 < NKS) { Bc[0] = Bn[0]; Bc[1] = Bn[1]; Bc[2] = Bn[2]; Bc[3] = Bn[3]; }
    }

    // ---------------- stream sdelta against acc (branchless, bulk-issued) ----------------
    // C/D layout: col = lane&15 (+nt*16), row m = mt*16 + (lane>>4)*4 + i  [verified r1/r2]
    float res0 = 0.f, res1 = 0.f;
    const int colb = lt * 128 + w * 32;
    const int l0 = colb + llo;
    const int l1 = colb + 16 + llo;
    const float lv0 = (l0 < LMAX) ? 1.f : 0.f;
    const float lv1 = (l1 < LMAX) ? 1.f : 0.f;
    const int l0s = (l0 < LMAX) ? l0 : (LMAX - 1);
    const int l1s = (l1 < LMAX) ? l1 : (LMAX - 1);
    const float* sdb = sdelta + (size_t)b * MLEN * LMAX * 2;
    #pragma unroll
    for (int mt = 0; mt < 7; ++mt) {
        #pragma unroll
        for (int i = 0; i < 4; ++i) {
            const int m  = mt * 16 + lhi * 4 + i;
            const int ms = (m < MLEN) ? m : 0;
            const float mv = (m < MLEN) ? 1.f : 0.f;
            const float* rp = sdb + (size_t)ms * (LMAX * 2);
            const float2 v0 = *reinterpret_cast<const float2*>(rp + (size_t)l0s * 2);
            const float2 v1 = *reinterpret_cast<const float2*>(rp + (size_t)l1s * 2);
            res0 += (mv * lv0) * (v0.x + v0.y) * acc[mt][0][i];
            res1 += (mv * lv1) * (v1.x + v1.y) * acc[mt][1][i];
        }
    }
    res0 += __shfl_xor(res0, 16);
    res0 += __shfl_xor(res0, 32);
    res1 += __shfl_xor(res1, 16);
    res1 += __shfl_xor(res1, 32);
    if (lhi == 0) {
        if (l0 < LMAX) out[(size_t)b * LMAX + l0] = res0;
        if (l1 < LMAX) out[(size_t)b * LMAX + l1] = res1;
    }
}

// ---------------- Fallback (ws too small): straightforward f32 compute ----------------
__global__ __launch_bounds__(256)
void fallback_kernel(const float* __restrict__ attn, const float* __restrict__ sdelta,
                     const float* __restrict__ embt, const float* __restrict__ vw,
                     float* __restrict__ out) {
    const int idx = blockIdx.x * 256 + threadIdx.x;
    if (idx >= NB * LMAX) return;
    const int b = idx / LMAX;
    const int l = idx % LMAX;
    float s = 0.f;
    for (int m = 0; m < MLEN; ++m) {
        const float* ar = attn + ((size_t)b * MLEN + m) * EMBD;
        const float* er = embt + (size_t)(l + 1) * EMBD;
        float dot = 0.f;
        for (int e = 0; e < EMBD; ++e) dot += ar[e] * er[e];
        const size_t so = (((size_t)b * MLEN + m) * LMAX + l) * 2;
        s += dot * vw[m] * (sdelta[so] + sdelta[so + 1]);
    }
    out[idx] = s;
}

extern "C" void kernel_launch(void* const* d_in, const int* in_sizes, int n_in,
                              void* d_out, int out_size, void* d_ws, size_t ws_size,
                              hipStream_t stream) {
    const float* attn   = (const float*)d_in[0];  // [16][100][256] f32
    const float* sdelta = (const float*)d_in[1];  // [16][100][20000][2] f32
    // d_in[2] = traj_len — unused by the reference computation
    const float* embt   = (const float*)d_in[3];  // [20001][256] f32
    const float* vw     = (const float*)d_in[4];  // [1][100] f32
    float* out = (float*)d_out;                   // [16][20000] f32

    const size_t bfragShorts = (size_t)NBFRAG * 512;  // 5,144,576
    const size_t afragShorts = (size_t)NAFRAG * 512;  //   458,752
    const size_t needed = (2 * bfragShorts + 2 * afragShorts) * sizeof(unsigned short); // 22,413,312 B

    if (ws_size >= needed) {
        unsigned short* Bhi = (unsigned short*)d_ws;
        unsigned short* Blo = Bhi + bfragShorts;
        unsigned short* Ahi = Blo + bfragShorts;
        unsigned short* Alo = Ahi + afragShorts;
        prep_kernel<<<PREP_BLOCKS, 256, 0, stream>>>(attn, embt, vw, Bhi, Blo, Ahi, Alo);
        main_kernel<<<dim3(NB, NLT), 256, 0, stream>>>(Bhi, Blo, Ahi, Alo, sdelta, out);
    } else {
        fallback_kernel<<<(NB * LMAX + 255) / 256, 256, 0, stream>>>(attn, sdelta, embt, vw, out);
    }
}

// Round 4
// 99.828 us; speedup vs baseline: 2.2504x; 1.1944x over previous
//
#include <hip/hip_runtime.h>

// Problem constants: B=16, MAX_LEN=100, LOC_MAX=20000, EMB=256, D_DELTA=2
#define NB 16
#define MLEN 100
#define EMBD 256
#define LMAX 20000
#define NLT 157            // l-tiles of 128 (157*128 = 20096)
#define NT16 1256          // n-tiles of 16  (NLT*8)
#define NKS 8              // K=256 / 32
#define NBFRAG (NT16 * NKS)      // 10048 B-fragments (64 lanes x 16B each)
#define NAFRAG (NB * NKS * 7)    // 896 A-fragments, layout [b][ks][mt]
#define BTASKS (NBFRAG * 64)     // 643072
#define ATASKS (NAFRAG * 64)     // 57344
#define PREP_BLOCKS ((BTASKS + ATASKS) / 256)  // 2736 exactly
#define PPITCH 130               // P row pitch (floats): even (8B align), 2-way park conflict only

typedef __attribute__((ext_vector_type(4))) float f32x4;
typedef __attribute__((ext_vector_type(8))) short bf16x8;
typedef const __attribute__((address_space(1))) unsigned int* as1_u32p;
typedef __attribute__((address_space(3))) unsigned int* as3_u32p;

__device__ __forceinline__ unsigned short f2bf(float x) {
    union { float f; unsigned u; } a; a.f = x;
    unsigned r = a.u + 0x7FFFu + ((a.u >> 16) & 1u);
    return (unsigned short)(r >> 16);
}
__device__ __forceinline__ float bf2f(unsigned short h) {
    union { unsigned u; float f; } a; a.u = ((unsigned)h) << 16;
    return a.f;
}

__device__ __forceinline__ void split8(f32x4 v0, f32x4 v1, float w, uint4& hi, uint4& lo) {
    float x[8] = { v0[0]*w, v0[1]*w, v0[2]*w, v0[3]*w, v1[0]*w, v1[1]*w, v1[2]*w, v1[3]*w };
    unsigned h[8], l[8];
    #pragma unroll
    for (int j = 0; j < 8; ++j) {
        unsigned short hh = f2bf(x[j]);
        h[j] = hh;
        l[j] = f2bf(x[j] - bf2f(hh));
    }
    hi = make_uint4(h[0] | (h[1] << 16), h[2] | (h[3] << 16), h[4] | (h[5] << 16), h[6] | (h[7] << 16));
    lo = make_uint4(l[0] | (l[1] << 16), l[2] | (l[3] << 16), l[4] | (l[5] << 16), l[6] | (l[7] << 16));
}

// ---------------- Kernel 1: one-time conversion + MFMA-fragment packing ----------------
// B frag f = t16*NKS+ks : emb_cand[t16*16 + (lane&15)][ks*32 + (lane>>4)*8 ..+8]
// A frag f = (b*NKS+ks)*7+mt : vw[m]*attn[b][m][..], m = mt*16 + (lane&15)   (ks-major)
__global__ __launch_bounds__(256)
void prep_kernel(const float* __restrict__ attn, const float* __restrict__ embt,
                 const float* __restrict__ vw,
                 unsigned short* __restrict__ Bhi, unsigned short* __restrict__ Blo,
                 unsigned short* __restrict__ Ahi, unsigned short* __restrict__ Alo) {
    const int gid = blockIdx.x * 256 + threadIdx.x;
    if (gid < BTASKS) {
        const int lane = gid & 63;
        const int f    = gid >> 6;
        const int ks   = f & 7;
        const int t16  = f >> 3;
        const int n    = t16 * 16 + (lane & 15);
        const int k    = ks * 32 + (lane >> 4) * 8;
        f32x4 v0 = {0.f,0.f,0.f,0.f}, v1 = {0.f,0.f,0.f,0.f};
        if (n < LMAX) {
            const float* p = embt + (size_t)(n + 1) * EMBD + k;
            v0 = *reinterpret_cast<const f32x4*>(p);
            v1 = *reinterpret_cast<const f32x4*>(p + 4);
        }
        uint4 hi, lo;
        split8(v0, v1, 1.f, hi, lo);
        reinterpret_cast<uint4*>(Bhi)[gid] = hi;
        reinterpret_cast<uint4*>(Blo)[gid] = lo;
    } else {
        const int gid2 = gid - BTASKS;
        const int lane = gid2 & 63;
        const int f    = gid2 >> 6;     // (b*NKS+ks)*7 + mt
        const int mt   = f % 7;
        const int t    = f / 7;
        const int ks   = t & 7;
        const int b    = t >> 3;
        const int m    = mt * 16 + (lane & 15);
        const int k    = ks * 32 + (lane >> 4) * 8;
        f32x4 v0 = {0.f,0.f,0.f,0.f}, v1 = {0.f,0.f,0.f,0.f};
        float w = 0.f;
        if (m < MLEN) {
            w = vw[m];
            const float* p = attn + ((size_t)b * MLEN + m) * EMBD + k;
            v0 = *reinterpret_cast<const f32x4*>(p);
            v1 = *reinterpret_cast<const f32x4*>(p + 4);
        }
        uint4 hi, lo;
        split8(v0, v1, w, hi, lo);
        reinterpret_cast<uint4*>(Ahi)[gid2] = hi;
        reinterpret_cast<uint4*>(Alo)[gid2] = lo;
    }
}

// ---------------- Kernel 2: LDS-staged pipelined GEMM + P-park + high-MLP sdelta stream ----------------
struct GemmLds { unsigned short Alds[2 * 14 * 512]; };       // 28672 B
struct StreamLds { float P2[MLEN * PPITCH]; float red[4 * 128]; };  // 52000 + 2048 = 54048 B
union LdsU { GemmLds g; StreamLds s; };

__global__ __launch_bounds__(256, 3)
void main_kernel(const unsigned short* __restrict__ Bhi, const unsigned short* __restrict__ Blo,
                 const unsigned short* __restrict__ Ahi, const unsigned short* __restrict__ Alo,
                 const float* __restrict__ sdelta, float* __restrict__ out) {
    __shared__ __align__(16) LdsU u;
    const int b    = blockIdx.x;
    const int lt   = blockIdx.y;
    const int w    = threadIdx.x >> 6;
    const int lane = threadIdx.x & 63;
    const int llo  = lane & 15;
    const int lhi  = lane >> 4;

    f32x4 acc[7][2];
    #pragma unroll
    for (int i = 0; i < 7; ++i) {
        acc[i][0] = (f32x4){0.f,0.f,0.f,0.f};
        acc[i][1] = (f32x4){0.f,0.f,0.f,0.f};
    }

    // async-stage A[b][ks] (14 frags: u<7 -> hi[mt=u], u>=7 -> lo[mt=u-7]) into Alds buf
    auto stageA = [&](int ks, int buf) {
        #pragma unroll
        for (int j = 0; j < 4; ++j) {
            const int uu = j * 4 + w;          // wave-uniform
            if (uu < 14) {
                const int mt = (uu < 7) ? uu : uu - 7;
                const unsigned short* base = (uu < 7) ? Ahi : Alo;
                const unsigned short* src = base + ((size_t)((b * NKS + ks) * 7 + mt)) * 512 + lane * 8;
                unsigned short* dst = &u.g.Alds[buf * 7168 + uu * 512];  // uniform base; HW adds lane*16B
                __builtin_amdgcn_global_load_lds((as1_u32p)(const void*)src,
                                                 (as3_u32p)(void*)dst, 16, 0, 0);
            }
        }
    };
    const int t16b = lt * 8 + w * 2;
    auto loadB = [&](int ks, bf16x8* dst) {
        const size_t bo0 = ((size_t)((t16b + 0) * NKS + ks) * 64 + lane) * 8;
        const size_t bo1 = ((size_t)((t16b + 1) * NKS + ks) * 64 + lane) * 8;
        dst[0] = *reinterpret_cast<const bf16x8*>(Bhi + bo0);
        dst[1] = *reinterpret_cast<const bf16x8*>(Blo + bo0);
        dst[2] = *reinterpret_cast<const bf16x8*>(Bhi + bo1);
        dst[3] = *reinterpret_cast<const bf16x8*>(Blo + bo1);
    };

    bf16x8 Bc[4], Bn[4];
    stageA(0, 0);
    loadB(0, Bc);
    __syncthreads();

    #pragma unroll
    for (int ks = 0; ks < NKS; ++ks) {
        if (ks + 1 < NKS) {
            stageA(ks + 1, (ks + 1) & 1);     // async into other buffer
            loadB(ks + 1, Bn);                // in-flight across the MFMA cluster
        }
        #pragma unroll
        for (int mt = 0; mt < 7; ++mt) {
            const bf16x8 ah = *reinterpret_cast<const bf16x8*>(&u.g.Alds[(ks & 1) * 7168 + mt * 512 + lane * 8]);
            const bf16x8 al = *reinterpret_cast<const bf16x8*>(&u.g.Alds[(ks & 1) * 7168 + (7 + mt) * 512 + lane * 8]);
            acc[mt][0] = __builtin_amdgcn_mfma_f32_16x16x32_bf16(ah, Bc[0], acc[mt][0], 0, 0, 0);
            acc[mt][1] = __builtin_amdgcn_mfma_f32_16x16x32_bf16(ah, Bc[2], acc[mt][1], 0, 0, 0);
            acc[mt][0] = __builtin_amdgcn_mfma_f32_16x16x32_bf16(ah, Bc[1], acc[mt][0], 0, 0, 0);
            acc[mt][1] = __builtin_amdgcn_mfma_f32_16x16x32_bf16(ah, Bc[3], acc[mt][1], 0, 0, 0);
            acc[mt][0] = __builtin_amdgcn_mfma_f32_16x16x32_bf16(al, Bc[0], acc[mt][0], 0, 0, 0);
            acc[mt][1] = __builtin_amdgcn_mfma_f32_16x16x32_bf16(al, Bc[2], acc[mt][1], 0, 0, 0);
        }
        __syncthreads();   // drains vmcnt (stage+Bn); also protects Alds before P-park overwrite at ks=7
        if (ks + 1 < NKS) { Bc[0] = Bn[0]; Bc[1] = Bn[1]; Bc[2] = Bn[2]; Bc[3] = Bn[3]; }
    }

    // ---------------- park P into LDS ----------------
    // C/D layout: col = lane&15 (+nt*16), row m = mt*16 + (lane>>4)*4 + i  [verified r1-r3]
    #pragma unroll
    for (int mt = 0; mt < 7; ++mt) {
        #pragma unroll
        for (int nt = 0; nt < 2; ++nt) {
            const int col = w * 32 + nt * 16 + llo;
            #pragma unroll
            for (int i = 0; i < 4; ++i) {
                const int m = mt * 16 + lhi * 4 + i;
                if (m < MLEN) u.s.P2[m * PPITCH + col] = acc[mt][nt][i];
            }
        }
    }
    __syncthreads();

    // ---------------- stream sdelta: lane owns l-pair (lp, lp+1); wave w does m = w+4i ----------------
    const int lp = 2 * lane;                       // tile-local l pair
    const int l0 = lt * 128 + lp;                  // global l of first elem
    const float msk0 = (l0     < LMAX) ? 1.f : 0.f;
    const float msk1 = (l0 + 1 < LMAX) ? 1.f : 0.f;
    const int lsafe  = (l0 + 1 < LMAX) ? l0 : (LMAX - 2);
    const float* sdb = sdelta + ((size_t)(b * MLEN) * LMAX + lsafe) * 2;

    // batch ALL 25 float4 loads up-front (static indices -> registers; 400 B/lane in flight)
    f32x4 v[25];
    #pragma unroll
    for (int i = 0; i < 25; ++i) {
        const int m = w + 4 * i;
        v[i] = *reinterpret_cast<const f32x4*>(sdb + (size_t)m * (LMAX * 2));
    }
    float accE = 0.f, accO = 0.f;
    #pragma unroll
    for (int i = 0; i < 25; ++i) {
        const int m = w + 4 * i;
        const float2 p = *reinterpret_cast<const float2*>(&u.s.P2[m * PPITCH + lp]);
        accE += (v[i][0] + v[i][1]) * p.x;
        accO += (v[i][2] + v[i][3]) * p.y;
    }
    *reinterpret_cast<float2*>(&u.s.red[w * 128 + lp]) = make_float2(accE * msk0, accO * msk1);
    __syncthreads();
    if (threadIdx.x < 128) {
        const int l = lt * 128 + threadIdx.x;
        if (l < LMAX) {
            const int t = threadIdx.x;
            float s = u.s.red[t] + u.s.red[128 + t] + u.s.red[256 + t] + u.s.red[384 + t];
            out[(size_t)b * LMAX + l] = s;
        }
    }
}

// ---------------- Fallback (ws too small): straightforward f32 compute ----------------
__global__ __launch_bounds__(256)
void fallback_kernel(const float* __restrict__ attn, const float* __restrict__ sdelta,
                     const float* __restrict__ embt, const float* __restrict__ vw,
                     float* __restrict__ out) {
    const int idx = blockIdx.x * 256 + threadIdx.x;
    if (idx >= NB * LMAX) return;
    const int b = idx / LMAX;
    const int l = idx % LMAX;
    float s = 0.f;
    for (int m = 0; m < MLEN; ++m) {
        const float* ar = attn + ((size_t)b * MLEN + m) * EMBD;
        const float* er = embt + (size_t)(l + 1) * EMBD;
        float dot = 0.f;
        for (int e = 0; e < EMBD; ++e) dot += ar[e] * er[e];
        const size_t so = (((size_t)b * MLEN + m) * LMAX + l) * 2;
        s += dot * vw[m] * (sdelta[so] + sdelta[so + 1]);
    }
    out[idx] = s;
}

extern "C" void kernel_launch(void* const* d_in, const int* in_sizes, int n_in,
                              void* d_out, int out_size, void* d_ws, size_t ws_size,
                              hipStream_t stream) {
    const float* attn   = (const float*)d_in[0];  // [16][100][256] f32
    const float* sdelta = (const float*)d_in[1];  // [16][100][20000][2] f32
    // d_in[2] = traj_len — unused by the reference computation
    const float* embt   = (const float*)d_in[3];  // [20001][256] f32
    const float* vw     = (const float*)d_in[4];  // [1][100] f32
    float* out = (float*)d_out;                   // [16][20000] f32

    const size_t bfragShorts = (size_t)NBFRAG * 512;  // 5,144,576
    const size_t afragShorts = (size_t)NAFRAG * 512;  //   458,752
    const size_t needed = (2 * bfragShorts + 2 * afragShorts) * sizeof(unsigned short); // 22,413,312 B

    if (ws_size >= needed) {
        unsigned short* Bhi = (unsigned short*)d_ws;
        unsigned short* Blo = Bhi + bfragShorts;
        unsigned short* Ahi = Blo + bfragShorts;
        unsigned short* Alo = Ahi + afragShorts;
        prep_kernel<<<PREP_BLOCKS, 256, 0, stream>>>(attn, embt, vw, Bhi, Blo, Ahi, Alo);
        main_kernel<<<dim3(NB, NLT), 256, 0, stream>>>(Bhi, Blo, Ahi, Alo, sdelta, out);
    } else {
        fallback_kernel<<<(NB * LMAX + 255) / 256, 256, 0, stream>>>(attn, sdelta, embt, vw, out);
    }
}